// Round 1
// baseline (269.293 us; speedup 1.0000x reference)
//
#include <hip/hip_runtime.h>

typedef __attribute__((ext_vector_type(8))) short short8;
typedef __attribute__((ext_vector_type(4))) float f32x4;

#define TT 2048   // sequence length
#define DM 1024   // model dim
#define NH 16     // query heads
#define NKV 4     // kv heads
#define HD 64     // head dim

__device__ __forceinline__ unsigned short f2bf(float x){
  unsigned int u = __float_as_uint(x);
  u += 0x7fffu + ((u >> 16) & 1u);   // round-to-nearest-even
  return (unsigned short)(u >> 16);
}

// ---------------- 1. fp32 -> bf16 conversion of inputs ----------------
// segments (vec4 units): x 524288 | q_w 262144 | k_w 65536 | v_w 65536 | o_w 262144
__global__ __launch_bounds__(256) void convert_kernel(
    const float* __restrict__ x,  const float* __restrict__ qw,
    const float* __restrict__ kw, const float* __restrict__ vw,
    const float* __restrict__ ow,
    unsigned short* __restrict__ xb, unsigned short* __restrict__ wqkv,
    unsigned short* __restrict__ owb){
  long v = (long)blockIdx.x * 256 + threadIdx.x;   // total 1179648
  const float* src; unsigned short* dst; long base;
  if      (v < 524288) { src = x;  dst = xb;             base = v; }
  else if (v < 786432) { src = qw; dst = wqkv;           base = v - 524288; }
  else if (v < 851968) { src = kw; dst = wqkv + 1048576; base = v - 786432; }
  else if (v < 917504) { src = vw; dst = wqkv + 1310720; base = v - 851968; }
  else                 { src = ow; dst = owb;            base = v - 917504; }
  f32x4 d = *(const f32x4*)(src + base * 4);
  ushort4 pk;
  pk.x = f2bf(d[0]); pk.y = f2bf(d[1]); pk.z = f2bf(d[2]); pk.w = f2bf(d[3]);
  *(ushort4*)(dst + base * 4) = pk;
}

// ---------------- 2/5. C[M,N] = A[M,K] * B[N,K]^T  (bf16 in, fp32 out) ----------------
// 128x128 block tile, 4 waves (2x2), each wave 4x4 MFMA tiles of 16x16x32.
__global__ __launch_bounds__(256) void gemm_bt(
    const unsigned short* __restrict__ A, const unsigned short* __restrict__ B,
    float* __restrict__ C, int M, int N, int K){
  __shared__ unsigned short As[128 * 32];
  __shared__ unsigned short Bs[128 * 32];
  const int tid  = threadIdx.x;
  const int lane = tid & 63;
  const int wave = tid >> 6;
  const int bm = blockIdx.y * 128, bn = blockIdx.x * 128;
  const int wm = (wave >> 1) * 64, wn = (wave & 1) * 64;
  const int ml = lane & 15, quad = lane >> 4;
  f32x4 acc[4][4];
  const f32x4 z = {0.f, 0.f, 0.f, 0.f};
#pragma unroll
  for (int i = 0; i < 4; i++)
#pragma unroll
    for (int j = 0; j < 4; j++) acc[i][j] = z;

  const int srow = tid >> 2, scol = (tid & 3) * 8;  // 256 thr x 16B = 4KB/pass
  const unsigned short* Ag = A + (long)(bm + srow) * K + scol;
  const unsigned short* Bg = B + (long)(bn + srow) * K + scol;

  for (int k0 = 0; k0 < K; k0 += 32){
    __syncthreads();
    *(uint4*)&As[srow * 32 + scol]        = *(const uint4*)(Ag + k0);
    *(uint4*)&As[(srow + 64) * 32 + scol] = *(const uint4*)(Ag + 64L * K + k0);
    *(uint4*)&Bs[srow * 32 + scol]        = *(const uint4*)(Bg + k0);
    *(uint4*)&Bs[(srow + 64) * 32 + scol] = *(const uint4*)(Bg + 64L * K + k0);
    __syncthreads();
    short8 a[4], b[4];
#pragma unroll
    for (int i = 0; i < 4; i++) a[i] = *(const short8*)&As[(wm + i * 16 + ml) * 32 + quad * 8];
#pragma unroll
    for (int j = 0; j < 4; j++) b[j] = *(const short8*)&Bs[(wn + j * 16 + ml) * 32 + quad * 8];
#pragma unroll
    for (int i = 0; i < 4; i++)
#pragma unroll
      for (int j = 0; j < 4; j++)
        acc[i][j] = __builtin_amdgcn_mfma_f32_16x16x32_bf16(a[i], b[j], acc[i][j], 0, 0, 0);
  }
#pragma unroll
  for (int i = 0; i < 4; i++)
#pragma unroll
    for (int j = 0; j < 4; j++)
#pragma unroll
      for (int r = 0; r < 4; r++){
        int row = bm + wm + i * 16 + quad * 4 + r;
        int col = bn + wn + j * 16 + ml;
        C[(long)row * N + col] = acc[i][j][r];
      }
}

// ---------------- 3. RMSNorm + RoPE + q0/k0 + V transpose + spatial partials ----------
// one wave per 64-elem head vector; slots per t: 16 q | 4 k | 4 v (24 total)
__global__ __launch_bounds__(256) void normrope_kernel(
    const float* __restrict__ qkv,
    unsigned short* __restrict__ qb, unsigned short* __restrict__ kb,
    unsigned short* __restrict__ vt,
    float* __restrict__ q0, float* __restrict__ k0,
    float* __restrict__ bpart, const float* __restrict__ curv){
  const int tid = threadIdx.x, lane = tid & 63, wave = tid >> 6;
  __shared__ float bsum;
  if (tid == 0) bsum = 0.f;
  __syncthreads();
  int wid  = blockIdx.x * 4 + wave;        // < 49152
  int t    = wid / 24;
  int slot = wid % 24;
  float c = curv[0];
  if (slot >= 20){                          // V: straight bf16 + transpose to [hk][d][t]
    int hk = slot - 20;
    float v = qkv[(long)t * 1536 + 1280 + hk * 64 + lane];
    vt[(long)(hk * 64 + lane) * TT + t] = f2bf(v);
  } else {
    bool isq = slot < 16;
    int h = isq ? slot : slot - 16;
    float val = qkv[(long)t * 1536 + (isq ? h * 64 : 1024 + h * 64) + lane];
    float ss = val * val;
#pragma unroll
    for (int off = 1; off < 64; off <<= 1) ss += __shfl_xor(ss, off);
    float scale = rsqrtf(ss * (1.f / 64.f) + 1e-6f);
    float xn = val * scale;
    float other = __shfl_xor(xn, 32);
    int fi = lane & 31;
    float invf = exp2f((float)fi * (-13.287712379549449f / 32.f));  // 10000^(-fi/32)
    float ang = (float)t * invf;
    float cs = cosf(ang), sn = sinf(ang);
    float outv = (lane < 32) ? (xn * cs + other * sn) : (xn * cs - other * sn);
    float sq = ss * scale * scale;            // |q_roped|^2 (rope preserves norm)
    float r0 = sqrtf(1.f / c + sq);
    if (isq){
      qb[((long)h * TT + t) * 64 + lane] = f2bf(outv);
      if (lane == 0){ q0[h * TT + t] = r0; atomicAdd(&bsum, sqrtf(sq)); }
    } else {
      kb[((long)h * TT + t) * 64 + lane] = f2bf(outv);
      if (lane == 0) k0[h * TT + t] = r0;
    }
  }
  __syncthreads();
  if (tid == 0) bpart[blockIdx.x] = bsum;
}

// ---------------- 4. fused hyperbolic causal attention ----------------
// block = 4 waves; wave w owns 16 q-rows (i0 = qb*64 + w*16); j-tiles of 32 keys.
__global__ __launch_bounds__(256) void attn_kernel(
    const unsigned short* __restrict__ qb_, const unsigned short* __restrict__ kb_,
    const unsigned short* __restrict__ vt_,
    const float* __restrict__ q0_, const float* __restrict__ k0_,
    const float* __restrict__ temp, const float* __restrict__ curv,
    unsigned short* __restrict__ attn_out){
  __shared__ float p_lds[4][16][44];   // stride 44 floats: 16B-aligned b128, ~2-4 way banks
  const int tid = threadIdx.x, lane = tid & 63, wave = tid >> 6;
  const int h  = blockIdx.x & 15;
  const int qi = blockIdx.x >> 4;
  const int qbi = (TT / 64 - 1) - qi;       // longest blocks dispatched first
  const int kvh = h >> 2;
  const int i0 = qbi * 64 + wave * 16;
  const int ml = lane & 15, quad = lane >> 4;
  const float c = curv[0];
  const float factor = -rsqrtf(c) / temp[h];   // score = factor * arccosh(arg)

  short8 qf0 = *(const short8*)&qb_[((long)h * TT + i0 + ml) * 64 + quad * 8];
  short8 qf1 = *(const short8*)&qb_[((long)h * TT + i0 + ml) * 64 + 32 + quad * 8];
  float q0v[4];
#pragma unroll
  for (int r = 0; r < 4; r++) q0v[r] = q0_[h * TT + i0 + quad * 4 + r];

  float m_st[4], l_st[4];
  f32x4 oa[4];
  const f32x4 z = {0.f, 0.f, 0.f, 0.f};
#pragma unroll
  for (int r = 0; r < 4; r++){ m_st[r] = -1e30f; l_st[r] = 0.f; }
#pragma unroll
  for (int dt = 0; dt < 4; dt++) oa[dt] = z;

  const int jmax = qbi * 64 + 64;
  for (int j0 = 0; j0 < jmax; j0 += 32){
    const unsigned short* kbase = kb_ + ((long)kvh * TT + j0) * 64;
    short8 ka0 = *(const short8*)(kbase + ml * 64 + quad * 8);
    short8 ka1 = *(const short8*)(kbase + ml * 64 + 32 + quad * 8);
    short8 kc0 = *(const short8*)(kbase + (16 + ml) * 64 + quad * 8);
    short8 kc1 = *(const short8*)(kbase + (16 + ml) * 64 + 32 + quad * 8);
    f32x4 s0 = z, s1 = z;
    s0 = __builtin_amdgcn_mfma_f32_16x16x32_bf16(qf0, ka0, s0, 0, 0, 0);
    s0 = __builtin_amdgcn_mfma_f32_16x16x32_bf16(qf1, ka1, s0, 0, 0, 0);
    s1 = __builtin_amdgcn_mfma_f32_16x16x32_bf16(qf0, kc0, s1, 0, 0, 0);
    s1 = __builtin_amdgcn_mfma_f32_16x16x32_bf16(qf1, kc1, s1, 0, 0, 0);

    float k0A = k0_[kvh * TT + j0 + ml];
    float k0B = k0_[kvh * TT + j0 + 16 + ml];
    int colA = j0 + ml, colB = j0 + 16 + ml;
    float mx[4];
#pragma unroll
    for (int r = 0; r < 4; r++){
      int row = i0 + quad * 4 + r;
      float minkA = s0[r] - q0v[r] * k0A;
      float argA = fmaxf(-c * minkA, 1.f + 1e-5f);
      float sa = factor * __logf(argA + sqrtf(__builtin_fmaf(argA, argA, -1.f)));
      if (colA > row) sa = -1e30f;
      float minkB = s1[r] - q0v[r] * k0B;
      float argB = fmaxf(-c * minkB, 1.f + 1e-5f);
      float sb = factor * __logf(argB + sqrtf(__builtin_fmaf(argB, argB, -1.f)));
      if (colB > row) sb = -1e30f;
      s0[r] = sa; s1[r] = sb;
      mx[r] = fmaxf(sa, sb);
    }
#pragma unroll
    for (int off = 1; off < 16; off <<= 1){
#pragma unroll
      for (int r = 0; r < 4; r++) mx[r] = fmaxf(mx[r], __shfl_xor(mx[r], off));
    }
    float p0[4], p1[4], rs[4];
#pragma unroll
    for (int r = 0; r < 4; r++){
      float mn = fmaxf(m_st[r], mx[r]);
      float al = __expf(m_st[r] - mn);
      p0[r] = __expf(s0[r] - mn);
      p1[r] = __expf(s1[r] - mn);
      m_st[r] = mn;
      l_st[r] *= al;
      rs[r] = p0[r] + p1[r];
#pragma unroll
      for (int dt = 0; dt < 4; dt++) oa[dt][r] *= al;
    }
#pragma unroll
    for (int off = 1; off < 16; off <<= 1){
#pragma unroll
      for (int r = 0; r < 4; r++) rs[r] += __shfl_xor(rs[r], off);
    }
#pragma unroll
    for (int r = 0; r < 4; r++) l_st[r] += rs[r];

    // P (C-layout) -> LDS -> A-layout fragment (wave-local, no block barrier)
#pragma unroll
    for (int r = 0; r < 4; r++){
      p_lds[wave][quad * 4 + r][ml]      = p0[r];
      p_lds[wave][quad * 4 + r][16 + ml] = p1[r];
    }
    __asm__ volatile("s_waitcnt lgkmcnt(0)" ::: "memory");
    f32x4 pa = *(const f32x4*)&p_lds[wave][ml][quad * 8];
    f32x4 pb = *(const f32x4*)&p_lds[wave][ml][quad * 8 + 4];
    short8 pf;
    pf[0] = (short)f2bf(pa[0]); pf[1] = (short)f2bf(pa[1]);
    pf[2] = (short)f2bf(pa[2]); pf[3] = (short)f2bf(pa[3]);
    pf[4] = (short)f2bf(pb[0]); pf[5] = (short)f2bf(pb[1]);
    pf[6] = (short)f2bf(pb[2]); pf[7] = (short)f2bf(pb[3]);
#pragma unroll
    for (int dt = 0; dt < 4; dt++){
      short8 vf = *(const short8*)&vt_[((long)(kvh * 64 + dt * 16 + ml)) * TT + j0 + quad * 8];
      oa[dt] = __builtin_amdgcn_mfma_f32_16x16x32_bf16(pf, vf, oa[dt], 0, 0, 0);
    }
  }
  // epilogue: O = acc / l  -> attn[t][h*64+d] bf16
#pragma unroll
  for (int dt = 0; dt < 4; dt++)
#pragma unroll
    for (int r = 0; r < 4; r++){
      int row = i0 + quad * 4 + r;
      attn_out[(long)row * 1024 + h * 64 + dt * 16 + ml] = f2bf(oa[dt][r] / l_st[r]);
    }
}

// ---------------- 6. spatial_norm finalize ----------------
__global__ __launch_bounds__(256) void finalize_kernel(
    const float* __restrict__ bpart, float* __restrict__ out_scalar){
  __shared__ float sdata[4];
  float s = 0.f;
  for (int i = threadIdx.x; i < 12288; i += 256) s += bpart[i];
#pragma unroll
  for (int off = 1; off < 64; off <<= 1) s += __shfl_xor(s, off);
  if ((threadIdx.x & 63) == 0) sdata[threadIdx.x >> 6] = s;
  __syncthreads();
  if (threadIdx.x == 0)
    out_scalar[0] = (sdata[0] + sdata[1] + sdata[2] + sdata[3]) * (1.f / 32768.f);
}

extern "C" void kernel_launch(void* const* d_in, const int* in_sizes, int n_in,
                              void* d_out, int out_size, void* d_ws, size_t ws_size,
                              hipStream_t stream){
  const float* x    = (const float*)d_in[0];
  const float* qw   = (const float*)d_in[1];
  const float* kw   = (const float*)d_in[2];
  const float* vw   = (const float*)d_in[3];
  const float* ow   = (const float*)d_in[4];
  const float* temp = (const float*)d_in[5];
  const float* curv = (const float*)d_in[6];
  float* out = (float*)d_out;

  char* ws = (char*)d_ws;
  size_t off = 0;
  auto alloc = [&](size_t bytes) -> char* {
    char* p = ws + off;
    off += (bytes + 255) & ~(size_t)255;
    return p;
  };
  unsigned short* xb   = (unsigned short*)alloc((size_t)TT * DM * 2);        // 4 MB
  unsigned short* wqkv = (unsigned short*)alloc((size_t)1536 * DM * 2);      // 3 MB
  unsigned short* owb  = (unsigned short*)alloc((size_t)DM * DM * 2);        // 2 MB
  float*          qkv  = (float*)alloc((size_t)TT * 1536 * 4);               // 12 MB
  unsigned short* qb   = (unsigned short*)alloc((size_t)NH * TT * HD * 2);   // 4 MB
  unsigned short* kb   = (unsigned short*)alloc((size_t)NKV * TT * HD * 2);  // 1 MB
  unsigned short* vt   = (unsigned short*)alloc((size_t)NKV * TT * HD * 2);  // 1 MB
  float*          q0   = (float*)alloc((size_t)NH * TT * 4);
  float*          k0   = (float*)alloc((size_t)NKV * TT * 4);
  unsigned short* attn = (unsigned short*)alloc((size_t)TT * DM * 2);        // 4 MB
  float*          bpart= (float*)alloc((size_t)12288 * 4);

  convert_kernel<<<4608, 256, 0, stream>>>(x, qw, kw, vw, ow, xb, wqkv, owb);
  gemm_bt<<<dim3(12, 16), 256, 0, stream>>>(xb, wqkv, qkv, TT, 1536, DM);
  normrope_kernel<<<12288, 256, 0, stream>>>(qkv, qb, kb, vt, q0, k0, bpart, curv);
  attn_kernel<<<512, 256, 0, stream>>>(qb, kb, vt, q0, k0, temp, curv, attn);
  gemm_bt<<<dim3(8, 16), 256, 0, stream>>>(attn, owb, out, TT, DM, DM);
  finalize_kernel<<<1, 256, 0, stream>>>(bpart, out + (size_t)TT * DM);
}

// Round 3
// 221.168 us; speedup vs baseline: 1.2176x; 1.2176x over previous
//
#include <hip/hip_runtime.h>

typedef __attribute__((ext_vector_type(8))) short short8;
typedef __attribute__((ext_vector_type(8))) unsigned short ushort8;
typedef __attribute__((ext_vector_type(4))) float f32x4;

#define TT 2048   // sequence length
#define DM 1024   // model dim
#define NH 16     // query heads
#define NKV 4     // kv heads
#define HD 64     // head dim

__device__ __forceinline__ unsigned short f2bf(float x){
  unsigned int u = __float_as_uint(x);
  u += 0x7fffu + ((u >> 16) & 1u);   // round-to-nearest-even
  return (unsigned short)(u >> 16);
}

// ---------------- 1. fp32 -> bf16 conversion of inputs ----------------
// segments (vec4 units): x 524288 | q_w 262144 | k_w 65536 | v_w 65536 | o_w 262144
__global__ __launch_bounds__(256) void convert_kernel(
    const float* __restrict__ x,  const float* __restrict__ qw,
    const float* __restrict__ kw, const float* __restrict__ vw,
    const float* __restrict__ ow,
    unsigned short* __restrict__ xb, unsigned short* __restrict__ wqkv,
    unsigned short* __restrict__ owb){
  long v = (long)blockIdx.x * 256 + threadIdx.x;   // total 1179648
  const float* src; unsigned short* dst; long base;
  if      (v < 524288) { src = x;  dst = xb;             base = v; }
  else if (v < 786432) { src = qw; dst = wqkv;           base = v - 524288; }
  else if (v < 851968) { src = kw; dst = wqkv + 1048576; base = v - 786432; }
  else if (v < 917504) { src = vw; dst = wqkv + 1310720; base = v - 851968; }
  else                 { src = ow; dst = owb;            base = v - 917504; }
  f32x4 d = *(const f32x4*)(src + base * 4);
  ushort4 pk;
  pk.x = f2bf(d[0]); pk.y = f2bf(d[1]); pk.z = f2bf(d[2]); pk.w = f2bf(d[3]);
  *(ushort4*)(dst + base * 4) = pk;
}

// ---------------- 2/5. C[M,N] = A[M,K] * B[N,K]^T  (bf16 in, fp32 out) ----------------
__global__ __launch_bounds__(256) void gemm_bt(
    const unsigned short* __restrict__ A, const unsigned short* __restrict__ B,
    float* __restrict__ C, int M, int N, int K){
  __shared__ unsigned short As[128 * 32];
  __shared__ unsigned short Bs[128 * 32];
  const int tid  = threadIdx.x;
  const int lane = tid & 63;
  const int wave = tid >> 6;
  const int bm = blockIdx.y * 128, bn = blockIdx.x * 128;
  const int wm = (wave >> 1) * 64, wn = (wave & 1) * 64;
  const int ml = lane & 15, quad = lane >> 4;
  f32x4 acc[4][4];
  const f32x4 z = {0.f, 0.f, 0.f, 0.f};
#pragma unroll
  for (int i = 0; i < 4; i++)
#pragma unroll
    for (int j = 0; j < 4; j++) acc[i][j] = z;

  const int srow = tid >> 2, scol = (tid & 3) * 8;
  const unsigned short* Ag = A + (long)(bm + srow) * K + scol;
  const unsigned short* Bg = B + (long)(bn + srow) * K + scol;

  for (int k0 = 0; k0 < K; k0 += 32){
    __syncthreads();
    *(uint4*)&As[srow * 32 + scol]        = *(const uint4*)(Ag + k0);
    *(uint4*)&As[(srow + 64) * 32 + scol] = *(const uint4*)(Ag + 64L * K + k0);
    *(uint4*)&Bs[srow * 32 + scol]        = *(const uint4*)(Bg + k0);
    *(uint4*)&Bs[(srow + 64) * 32 + scol] = *(const uint4*)(Bg + 64L * K + k0);
    __syncthreads();
    short8 a[4], b[4];
#pragma unroll
    for (int i = 0; i < 4; i++) a[i] = *(const short8*)&As[(wm + i * 16 + ml) * 32 + quad * 8];
#pragma unroll
    for (int j = 0; j < 4; j++) b[j] = *(const short8*)&Bs[(wn + j * 16 + ml) * 32 + quad * 8];
#pragma unroll
    for (int i = 0; i < 4; i++)
#pragma unroll
      for (int j = 0; j < 4; j++)
        acc[i][j] = __builtin_amdgcn_mfma_f32_16x16x32_bf16(a[i], b[j], acc[i][j], 0, 0, 0);
  }
#pragma unroll
  for (int i = 0; i < 4; i++)
#pragma unroll
    for (int j = 0; j < 4; j++)
#pragma unroll
      for (int r = 0; r < 4; r++){
        int row = bm + wm + i * 16 + quad * 4 + r;
        int col = bn + wn + j * 16 + ml;
        C[(long)row * N + col] = acc[i][j][r];
      }
}

// ---------------- 3. RMSNorm + RoPE + q0/k0 + spatial partials (q/k only) ----------
// slots per t: 16 q | 4 k  (20 total); wids = 2048*20 = 40960; 10240 blocks
__global__ __launch_bounds__(256) void normrope_kernel(
    const float* __restrict__ qkv,
    unsigned short* __restrict__ qb, unsigned short* __restrict__ kb,
    float* __restrict__ q0, float* __restrict__ k0,
    float* __restrict__ bpart, const float* __restrict__ curv){
  const int tid = threadIdx.x, lane = tid & 63, wave = tid >> 6;
  __shared__ float bsum;
  if (tid == 0) bsum = 0.f;
  __syncthreads();
  int wid  = blockIdx.x * 4 + wave;        // < 40960
  int t    = wid / 20;
  int slot = wid - t * 20;
  float c = curv[0];
  bool isq = slot < 16;
  int h = isq ? slot : slot - 16;
  float val = qkv[(long)t * 1536 + (isq ? h * 64 : 1024 + h * 64) + lane];
  float ss = val * val;
#pragma unroll
  for (int off = 1; off < 64; off <<= 1) ss += __shfl_xor(ss, off);
  float scale = rsqrtf(ss * (1.f / 64.f) + 1e-6f);
  float xn = val * scale;
  float other = __shfl_xor(xn, 32);
  int fi = lane & 31;
  float invf = exp2f((float)fi * (-13.287712379549449f / 32.f));  // 10000^(-fi/32)
  float ang = (float)t * invf;
  float cs = cosf(ang), sn = sinf(ang);
  float outv = (lane < 32) ? (xn * cs + other * sn) : (xn * cs - other * sn);
  float sq = ss * scale * scale;            // |q_roped|^2 (rope preserves norm)
  float r0 = sqrtf(1.f / c + sq);
  if (isq){
    qb[((long)h * TT + t) * 64 + lane] = f2bf(outv);
    if (lane == 0){ q0[h * TT + t] = r0; atomicAdd(&bsum, sqrtf(sq)); }
  } else {
    kb[((long)h * TT + t) * 64 + lane] = f2bf(outv);
    if (lane == 0) k0[h * TT + t] = r0;
  }
  __syncthreads();
  if (tid == 0) bpart[blockIdx.x] = bsum;
}

// ---------------- 3b. V: bf16 convert + transpose to [hk][d][t] (LDS tiled) ----------
// grid: hk(4) x t-tile(32) = 128 blocks
__global__ __launch_bounds__(256) void vtrans_kernel(
    const float* __restrict__ qkv, unsigned short* __restrict__ vt){
  __shared__ unsigned short vs[64][72];    // pad 72: 144B row stride, 16B aligned
  const int tid = threadIdx.x;
  const int hk = blockIdx.x >> 5, tt = blockIdx.x & 31;
  const int t0 = tt * 64;
  {
    const int tl = tid >> 2, d0 = (tid & 3) * 16;
    const float* src = qkv + (long)(t0 + tl) * 1536 + 1280 + hk * 64 + d0;
    ushort8 pk0, pk1;
#pragma unroll
    for (int i = 0; i < 8; i++) pk0[i] = f2bf(src[i]);
#pragma unroll
    for (int i = 0; i < 8; i++) pk1[i] = f2bf(src[8 + i]);
    *(ushort8*)&vs[tl][d0]     = pk0;
    *(ushort8*)&vs[tl][d0 + 8] = pk1;
  }
  __syncthreads();
  {
    const int dr = tid >> 2, t4 = (tid & 3) * 16;
    ushort8 o0, o1;
#pragma unroll
    for (int i = 0; i < 8; i++) o0[i] = vs[t4 + i][dr];
#pragma unroll
    for (int i = 0; i < 8; i++) o1[i] = vs[t4 + 8 + i][dr];
    unsigned short* dst = vt + (long)(hk * 64 + dr) * TT + t0 + t4;
    *(ushort8*)dst       = o0;
    *(ushort8*)(dst + 8) = o1;
  }
}

// ---------------- 4. fused hyperbolic causal attention ----------------
// block = 16 q-rows of one head; 4 waves split the j-tiles (stride-4).
// No online max needed: score = -arccosh(arg)/temp <= 0 and diagonal score == 0,
// so p = exp(score) in (0,1] and denominator >= 1. p = w^factor = exp2(factor*log2(w)).
__global__ __launch_bounds__(256) void attn_kernel(
    const unsigned short* __restrict__ qb_, const unsigned short* __restrict__ kb_,
    const unsigned short* __restrict__ vt_,
    const float* __restrict__ q0_, const float* __restrict__ k0_,
    const float* __restrict__ temp, const float* __restrict__ curv,
    unsigned short* __restrict__ attn_out){
  // per-wave private region: 1104 floats. Inside loop: P tile [16][44].
  // After loop (same wave, sequential): merge O [16][68] + l [16] at +1088.
  __shared__ float lds[4 * 1104];
  const int tid = threadIdx.x, lane = tid & 63, wave = tid >> 6;
  float* wlds = lds + wave * 1104;
  const int h   = blockIdx.x & 15;
  const int qt  = 127 - (blockIdx.x >> 4);   // longest first
  const int i0  = qt * 16;
  const int kvh = h >> 2;
  const int ml = lane & 15, quad = lane >> 4;
  const float c = curv[0];
  const float factor = -rsqrtf(c) / temp[h];

  short8 qf0 = *(const short8*)&qb_[((long)h * TT + i0 + ml) * 64 + quad * 8];
  short8 qf1 = *(const short8*)&qb_[((long)h * TT + i0 + ml) * 64 + 32 + quad * 8];
  float q0c[4];
#pragma unroll
  for (int r = 0; r < 4; r++) q0c[r] = c * q0_[h * TT + i0 + quad * 4 + r];

  f32x4 oa[4];
  const f32x4 z = {0.f, 0.f, 0.f, 0.f};
#pragma unroll
  for (int dt = 0; dt < 4; dt++) oa[dt] = z;
  float l_part[4] = {0.f, 0.f, 0.f, 0.f};

  const int nt = (i0 + 47) >> 5;    // ceil((i0+16)/32) 32-key tiles
  for (int t = wave; t < nt; t += 4){
    const int j0 = t << 5;
    const unsigned short* kbase = kb_ + ((long)kvh * TT + j0) * 64;
    short8 ka0 = *(const short8*)(kbase + ml * 64 + quad * 8);
    short8 ka1 = *(const short8*)(kbase + ml * 64 + 32 + quad * 8);
    short8 kc0 = *(const short8*)(kbase + (16 + ml) * 64 + quad * 8);
    short8 kc1 = *(const short8*)(kbase + (16 + ml) * 64 + 32 + quad * 8);
    f32x4 s0 = z, s1 = z;
    s0 = __builtin_amdgcn_mfma_f32_16x16x32_bf16(qf0, ka0, s0, 0, 0, 0);
    s0 = __builtin_amdgcn_mfma_f32_16x16x32_bf16(qf1, ka1, s0, 0, 0, 0);
    s1 = __builtin_amdgcn_mfma_f32_16x16x32_bf16(qf0, kc0, s1, 0, 0, 0);
    s1 = __builtin_amdgcn_mfma_f32_16x16x32_bf16(qf1, kc1, s1, 0, 0, 0);

    const float k0A = k0_[kvh * TT + j0 + ml];
    const float k0B = k0_[kvh * TT + j0 + 16 + ml];
    const bool need_mask = (j0 + 31 > i0);
    float p0[4], p1[4];
#pragma unroll
    for (int r = 0; r < 4; r++){
      const int row = i0 + quad * 4 + r;
      float argA = fmaxf(__builtin_fmaf(-c, s0[r], q0c[r] * k0A), 1.00001f);
      float wA   = argA + sqrtf(__builtin_fmaf(argA, argA, -1.f));
      float pA   = __builtin_amdgcn_exp2f(factor * __builtin_amdgcn_logf(wA));
      float argB = fmaxf(__builtin_fmaf(-c, s1[r], q0c[r] * k0B), 1.00001f);
      float wB   = argB + sqrtf(__builtin_fmaf(argB, argB, -1.f));
      float pB   = __builtin_amdgcn_exp2f(factor * __builtin_amdgcn_logf(wB));
      if (need_mask){
        if (j0 + ml > row)      pA = 0.f;
        if (j0 + 16 + ml > row) pB = 0.f;
      }
      p0[r] = pA; p1[r] = pB;
      l_part[r] += pA + pB;
    }
    // P (C-layout) -> LDS -> A-layout bf16 fragment (wave-local)
#pragma unroll
    for (int r = 0; r < 4; r++){
      wlds[(quad * 4 + r) * 44 + ml]      = p0[r];
      wlds[(quad * 4 + r) * 44 + 16 + ml] = p1[r];
    }
    __asm__ volatile("s_waitcnt lgkmcnt(0)" ::: "memory");
    f32x4 pa = *(const f32x4*)&wlds[ml * 44 + quad * 8];
    f32x4 pb = *(const f32x4*)&wlds[ml * 44 + quad * 8 + 4];
    short8 pf;
    pf[0] = (short)f2bf(pa[0]); pf[1] = (short)f2bf(pa[1]);
    pf[2] = (short)f2bf(pa[2]); pf[3] = (short)f2bf(pa[3]);
    pf[4] = (short)f2bf(pb[0]); pf[5] = (short)f2bf(pb[1]);
    pf[6] = (short)f2bf(pb[2]); pf[7] = (short)f2bf(pb[3]);
#pragma unroll
    for (int dt = 0; dt < 4; dt++){
      short8 vf = *(const short8*)&vt_[((long)(kvh * 64 + dt * 16 + ml)) * TT + j0 + quad * 8];
      oa[dt] = __builtin_amdgcn_mfma_f32_16x16x32_bf16(pf, vf, oa[dt], 0, 0, 0);
    }
  }
  // finish per-lane l: reduce over the 16 cols (lanes of the quad-row group)
#pragma unroll
  for (int off = 1; off < 16; off <<= 1){
#pragma unroll
    for (int r = 0; r < 4; r++) l_part[r] += __shfl_xor(l_part[r], off);
  }
  // publish this wave's partial O and l (only clobbers our own p region)
#pragma unroll
  for (int dt = 0; dt < 4; dt++)
#pragma unroll
    for (int r = 0; r < 4; r++)
      wlds[(quad * 4 + r) * 68 + dt * 16 + ml] = oa[dt][r];
  if (ml == 0){
#pragma unroll
    for (int r = 0; r < 4; r++) wlds[1088 + quad * 4 + r] = l_part[r];
  }
  __syncthreads();
  // combine 4 waves: thread (row = tid>>4, cols c0..c0+3)
  {
    const int row = tid >> 4, c0 = (tid & 15) * 4;
    float L = lds[1088 + row] + lds[1104 + 1088 + row] +
              lds[2208 + 1088 + row] + lds[3312 + 1088 + row];
    f32x4 s = *(const f32x4*)&lds[row * 68 + c0];
#pragma unroll
    for (int w = 1; w < 4; w++){
      f32x4 t2 = *(const f32x4*)&lds[w * 1104 + row * 68 + c0];
      s[0] += t2[0]; s[1] += t2[1]; s[2] += t2[2]; s[3] += t2[3];
    }
    float invL = 1.f / L;
    ushort4 o;
    o.x = f2bf(s[0] * invL); o.y = f2bf(s[1] * invL);
    o.z = f2bf(s[2] * invL); o.w = f2bf(s[3] * invL);
    *(ushort4*)&attn_out[(long)(i0 + row) * 1024 + h * 64 + c0] = o;
  }
}

// ---------------- 6. spatial_norm finalize ----------------
__global__ __launch_bounds__(256) void finalize_kernel(
    const float* __restrict__ bpart, float* __restrict__ out_scalar){
  __shared__ float sdata[4];
  float s = 0.f;
  for (int i = threadIdx.x; i < 10240; i += 256) s += bpart[i];
#pragma unroll
  for (int off = 1; off < 64; off <<= 1) s += __shfl_xor(s, off);
  if ((threadIdx.x & 63) == 0) sdata[threadIdx.x >> 6] = s;
  __syncthreads();
  if (threadIdx.x == 0)
    out_scalar[0] = (sdata[0] + sdata[1] + sdata[2] + sdata[3]) * (1.f / 32768.f);
}

extern "C" void kernel_launch(void* const* d_in, const int* in_sizes, int n_in,
                              void* d_out, int out_size, void* d_ws, size_t ws_size,
                              hipStream_t stream){
  const float* x    = (const float*)d_in[0];
  const float* qw   = (const float*)d_in[1];
  const float* kw   = (const float*)d_in[2];
  const float* vw   = (const float*)d_in[3];
  const float* ow   = (const float*)d_in[4];
  const float* temp = (const float*)d_in[5];
  const float* curv = (const float*)d_in[6];
  float* out = (float*)d_out;

  char* ws = (char*)d_ws;
  size_t off = 0;
  auto alloc = [&](size_t bytes) -> char* {
    char* p = ws + off;
    off += (bytes + 255) & ~(size_t)255;
    return p;
  };
  unsigned short* xb   = (unsigned short*)alloc((size_t)TT * DM * 2);        // 4 MB
  unsigned short* wqkv = (unsigned short*)alloc((size_t)1536 * DM * 2);      // 3 MB
  unsigned short* owb  = (unsigned short*)alloc((size_t)DM * DM * 2);        // 2 MB
  float*          qkv  = (float*)alloc((size_t)TT * 1536 * 4);               // 12 MB
  unsigned short* qb   = (unsigned short*)alloc((size_t)NH * TT * HD * 2);   // 4 MB
  unsigned short* kb   = (unsigned short*)alloc((size_t)NKV * TT * HD * 2);  // 1 MB
  unsigned short* vt   = (unsigned short*)alloc((size_t)NKV * TT * HD * 2);  // 1 MB
  float*          q0   = (float*)alloc((size_t)NH * TT * 4);
  float*          k0   = (float*)alloc((size_t)NKV * TT * 4);
  unsigned short* attn = (unsigned short*)alloc((size_t)TT * DM * 2);        // 4 MB
  float*          bpart= (float*)alloc((size_t)10240 * 4);

  convert_kernel<<<4608, 256, 0, stream>>>(x, qw, kw, vw, ow, xb, wqkv, owb);
  gemm_bt<<<dim3(12, 16), 256, 0, stream>>>(xb, wqkv, qkv, TT, 1536, DM);
  normrope_kernel<<<10240, 256, 0, stream>>>(qkv, qb, kb, q0, k0, bpart, curv);
  vtrans_kernel<<<128, 256, 0, stream>>>(qkv, vt);
  attn_kernel<<<2048, 256, 0, stream>>>(qb, kb, vt, q0, k0, temp, curv, attn);
  gemm_bt<<<dim3(8, 16), 256, 0, stream>>>(attn, owb, out, TT, DM, DM);
  finalize_kernel<<<1, 256, 0, stream>>>(bpart, out + (size_t)TT * DM);
}

// Round 4
// 191.451 us; speedup vs baseline: 1.4066x; 1.1552x over previous
//
#include <hip/hip_runtime.h>
#include <hip/hip_bf16.h>

typedef __attribute__((ext_vector_type(8))) short short8;
typedef __attribute__((ext_vector_type(4))) float f32x4;
typedef __attribute__((ext_vector_type(2))) float f32x2;

#define TT 2048   // sequence length
#define DM 1024   // model dim
#define NH 16     // query heads
#define NKV 4     // kv heads
#define HD 64     // head dim

__device__ __forceinline__ unsigned short f2bf(float x){
  unsigned int u = __float_as_uint(x);
  u += 0x7fffu + ((u >> 16) & 1u);   // RNE
  return (unsigned short)(u >> 16);
}
// packed 2xfp32 -> 2xbf16 (v_cvt_pk_bf16_f32 on gfx950)
__device__ __forceinline__ unsigned int pkbf2(float x, float y){
  union { __hip_bfloat162 h; unsigned int u; } t;
  t.h = __float22bfloat162_rn(make_float2(x, y));
  return t.u;
}

// ---------------- 1. weights fp32 -> bf16 ----------------
// vec4 units: q_w 262144 | k_w 65536 | v_w 65536 | o_w 262144  (total 655360)
__global__ __launch_bounds__(256) void convertw_kernel(
    const float* __restrict__ qw, const float* __restrict__ kw,
    const float* __restrict__ vw, const float* __restrict__ ow,
    unsigned short* __restrict__ wqkv, unsigned short* __restrict__ owb){
  long v = (long)blockIdx.x * 256 + threadIdx.x;
  const float* src; unsigned short* dst; long base;
  if      (v < 262144) { src = qw; dst = wqkv;           base = v; }
  else if (v < 327680) { src = kw; dst = wqkv + 1048576; base = v - 262144; }
  else if (v < 393216) { src = vw; dst = wqkv + 1310720; base = v - 327680; }
  else                 { src = ow; dst = owb;            base = v - 393216; }
  f32x4 d = *(const f32x4*)(src + base * 4);
  uint2 pk = { pkbf2(d[0], d[1]), pkbf2(d[2], d[3]) };
  *(uint2*)(dst + base * 4) = pk;
}

// ---------------- 2. QKV GEMM (A=x fp32, inline cvt) + fused RMSNorm/RoPE/q0k0/Vtrans ----
// grid dim3(24, 32): x = head-block (0..15 q | 16..19 k | 20..23 v), y = 64-row t-tile
__global__ __launch_bounds__(256) void gemm1_fused(
    const float* __restrict__ x, const unsigned short* __restrict__ wqkv,
    unsigned short* __restrict__ qb, unsigned short* __restrict__ kb,
    unsigned short* __restrict__ vt,
    float* __restrict__ q0, float* __restrict__ k0,
    float* __restrict__ bpart, const float* __restrict__ curv){
  __shared__ float smemf[4160];                 // 16640 B: staging(8KB) then Ct[64][65]
  unsigned short* As = (unsigned short*)smemf;  // [64][32]
  unsigned short* Bs = As + 2048;               // [64][32]
  float* Ct = smemf;
  __shared__ float bsum;
  const int tid = threadIdx.x, lane = tid & 63, wave = tid >> 6;
  const int hIdx = blockIdx.x;
  const int bm = blockIdx.y * 64, bn = hIdx * 64;
  const int wm = (wave >> 1) * 32, wn = (wave & 1) * 32;
  const int ml = lane & 15, quad = lane >> 4;
  if (tid == 0) bsum = 0.f;
  f32x4 acc[2][2];
  const f32x4 z = {0.f, 0.f, 0.f, 0.f};
  acc[0][0] = z; acc[0][1] = z; acc[1][0] = z; acc[1][1] = z;

  const int srow = tid >> 2, scol = (tid & 3) * 8;
  const float* Ag = x + (long)(bm + srow) * 1024 + scol;
  const unsigned short* Bg = wqkv + (long)(bn + srow) * 1024 + scol;

  for (int kk = 0; kk < 1024; kk += 32){
    __syncthreads();
    f32x4 a0 = *(const f32x4*)(Ag + kk);
    f32x4 a1 = *(const f32x4*)(Ag + kk + 4);
    uint4 ap = { pkbf2(a0[0],a0[1]), pkbf2(a0[2],a0[3]),
                 pkbf2(a1[0],a1[1]), pkbf2(a1[2],a1[3]) };
    *(uint4*)&As[srow * 32 + scol] = ap;
    *(uint4*)&Bs[srow * 32 + scol] = *(const uint4*)(Bg + kk);
    __syncthreads();
    short8 a0f = *(const short8*)&As[(wm + ml) * 32 + quad * 8];
    short8 a1f = *(const short8*)&As[(wm + 16 + ml) * 32 + quad * 8];
    short8 b0f = *(const short8*)&Bs[(wn + ml) * 32 + quad * 8];
    short8 b1f = *(const short8*)&Bs[(wn + 16 + ml) * 32 + quad * 8];
    acc[0][0] = __builtin_amdgcn_mfma_f32_16x16x32_bf16(a0f, b0f, acc[0][0], 0, 0, 0);
    acc[0][1] = __builtin_amdgcn_mfma_f32_16x16x32_bf16(a0f, b1f, acc[0][1], 0, 0, 0);
    acc[1][0] = __builtin_amdgcn_mfma_f32_16x16x32_bf16(a1f, b0f, acc[1][0], 0, 0, 0);
    acc[1][1] = __builtin_amdgcn_mfma_f32_16x16x32_bf16(a1f, b1f, acc[1][1], 0, 0, 0);
  }
  __syncthreads();      // staging region -> Ct reuse
#pragma unroll
  for (int i = 0; i < 2; i++)
#pragma unroll
    for (int j = 0; j < 2; j++)
#pragma unroll
      for (int r = 0; r < 4; r++)
        Ct[(wm + i * 16 + quad * 4 + r) * 65 + wn + j * 16 + ml] = acc[i][j][r];
  __syncthreads();

  if (hIdx < 20){
    // RMSNorm + RoPE + q0/k0 (+ spatial partial for q). lane = head-dim d.
    const bool isq = hIdx < 16;
    const int h = isq ? hIdx : hIdx - 16;
    const float c = curv[0];
    unsigned short* ob = isq ? qb : kb;
    float* o0 = isq ? q0 : k0;
#pragma unroll 1
    for (int rr = 0; rr < 16; rr++){
      const int row = wave * 16 + rr;
      const int t = bm + row;
      float val = Ct[row * 65 + lane];
      float ss = val * val;
#pragma unroll
      for (int off = 1; off < 64; off <<= 1) ss += __shfl_xor(ss, off);
      float scale = __builtin_amdgcn_rsqf(ss * (1.f / 64.f) + 1e-6f);
      float xn = val * scale;
      float other = __shfl_xor(xn, 32);
      int fi = lane & 31;
      float ang = (float)t * __builtin_amdgcn_exp2f((float)fi * (-13.287712379549449f / 32.f));
      float sn, cs; __sincosf(ang, &sn, &cs);
      float outv = (lane < 32) ? (xn * cs + other * sn) : (xn * cs - other * sn);
      ob[((long)h * TT + t) * 64 + lane] = f2bf(outv);
      if (lane == 0){
        float sq = ss * scale * scale;      // |normed|^2, rope preserves norm
        o0[h * TT + t] = __builtin_amdgcn_sqrtf(1.f / c + sq);
        if (isq) atomicAdd(&bsum, __builtin_amdgcn_sqrtf(sq));
      }
    }
  } else {
    // V: bf16 + transpose to vt[hk][d][t]
    const int hk = hIdx - 20;
    const int d = tid >> 2, tseg = (tid & 3) * 16;
    uint4 w0, w1;
    w0.x = pkbf2(Ct[(tseg + 0) * 65 + d], Ct[(tseg + 1) * 65 + d]);
    w0.y = pkbf2(Ct[(tseg + 2) * 65 + d], Ct[(tseg + 3) * 65 + d]);
    w0.z = pkbf2(Ct[(tseg + 4) * 65 + d], Ct[(tseg + 5) * 65 + d]);
    w0.w = pkbf2(Ct[(tseg + 6) * 65 + d], Ct[(tseg + 7) * 65 + d]);
    w1.x = pkbf2(Ct[(tseg + 8) * 65 + d], Ct[(tseg + 9) * 65 + d]);
    w1.y = pkbf2(Ct[(tseg +10) * 65 + d], Ct[(tseg +11) * 65 + d]);
    w1.z = pkbf2(Ct[(tseg +12) * 65 + d], Ct[(tseg +13) * 65 + d]);
    w1.w = pkbf2(Ct[(tseg +14) * 65 + d], Ct[(tseg +15) * 65 + d]);
    unsigned short* dst = vt + (long)(hk * 64 + d) * TT + bm + tseg;
    *(uint4*)dst = w0;
    *(uint4*)(dst + 8) = w1;
  }
  __syncthreads();
  if (tid == 0) bpart[blockIdx.y * 24 + hIdx] = bsum;
}

// ---------------- 3. balanced fused hyperbolic causal attention (+finalize tail) -------
// block = 512 thr (8 waves); handles q-tiles {127-pair, pair} -> exactly 65 j-tiles/block.
// p = exp(score) in (0,1], diag p=1 => no online max needed.
__global__ __launch_bounds__(512) void attn_kernel(
    const unsigned short* __restrict__ qb_, const unsigned short* __restrict__ kb_,
    const unsigned short* __restrict__ vt_,
    const float* __restrict__ q0_, const float* __restrict__ k0_,
    const float* __restrict__ temp, const float* __restrict__ curv,
    unsigned short* __restrict__ attn_out,
    const float* __restrict__ bpart, float* __restrict__ out_scalar){
  __shared__ float lds[8 * 1104];    // per-wave: P[16][44] in loop; O[16][68]+l[16] merge
  const int tid = threadIdx.x, lane = tid & 63, wave = tid >> 6;
  float* wlds = lds + wave * 1104;
  const int h = blockIdx.x & 15, pair = blockIdx.x >> 4;
  const int kvh = h >> 2;
  const int ml = lane & 15, quad = lane >> 4;
  const float c = curv[0];
  const float factor = -1.f / (__builtin_amdgcn_sqrtf(c) * temp[h]);
  const f32x4 z = {0.f, 0.f, 0.f, 0.f};

#pragma unroll 1
  for (int ph = 0; ph < 2; ph++){
    const int qt = ph ? pair : 127 - pair;
    const int i0 = qt * 16;
    short8 qf0 = *(const short8*)&qb_[((long)h * TT + i0 + ml) * 64 + quad * 8];
    short8 qf1 = *(const short8*)&qb_[((long)h * TT + i0 + ml) * 64 + 32 + quad * 8];
    float q0c[4];
#pragma unroll
    for (int r = 0; r < 4; r++) q0c[r] = c * q0_[h * TT + i0 + quad * 4 + r];
    f32x4 oa[4];
#pragma unroll
    for (int dt = 0; dt < 4; dt++) oa[dt] = z;
    float l_part[4] = {0.f, 0.f, 0.f, 0.f};

    const int nt = (i0 + 47) >> 5;
    for (int t = wave; t < nt; t += 8){
      const int j0 = t << 5;
      const unsigned short* kbase = kb_ + ((long)kvh * TT + j0) * 64;
      short8 ka0 = *(const short8*)(kbase + ml * 64 + quad * 8);
      short8 ka1 = *(const short8*)(kbase + ml * 64 + 32 + quad * 8);
      short8 kc0 = *(const short8*)(kbase + (16 + ml) * 64 + quad * 8);
      short8 kc1 = *(const short8*)(kbase + (16 + ml) * 64 + 32 + quad * 8);
      f32x4 s0 = z, s1 = z;
      s0 = __builtin_amdgcn_mfma_f32_16x16x32_bf16(qf0, ka0, s0, 0, 0, 0);
      s0 = __builtin_amdgcn_mfma_f32_16x16x32_bf16(qf1, ka1, s0, 0, 0, 0);
      s1 = __builtin_amdgcn_mfma_f32_16x16x32_bf16(qf0, kc0, s1, 0, 0, 0);
      s1 = __builtin_amdgcn_mfma_f32_16x16x32_bf16(qf1, kc1, s1, 0, 0, 0);

      const float k0A = k0_[kvh * TT + j0 + ml];
      const float k0B = k0_[kvh * TT + j0 + 16 + ml];
      const bool need_mask = (j0 + 31 > i0);
      float p0[4], p1[4];
#pragma unroll
      for (int r = 0; r < 4; r++){
        const int row = i0 + quad * 4 + r;
        float argA = fmaxf(__builtin_fmaf(-c, s0[r], q0c[r] * k0A), 1.00001f);
        float wA   = argA + __builtin_amdgcn_sqrtf(__builtin_fmaf(argA, argA, -1.f));
        float pA   = __builtin_amdgcn_exp2f(factor * __builtin_amdgcn_logf(wA));
        float argB = fmaxf(__builtin_fmaf(-c, s1[r], q0c[r] * k0B), 1.00001f);
        float wB   = argB + __builtin_amdgcn_sqrtf(__builtin_fmaf(argB, argB, -1.f));
        float pB   = __builtin_amdgcn_exp2f(factor * __builtin_amdgcn_logf(wB));
        if (need_mask){
          if (j0 + ml > row)      pA = 0.f;
          if (j0 + 16 + ml > row) pB = 0.f;
        }
        p0[r] = pA; p1[r] = pB;
        l_part[r] += pA + pB;
      }
      // P (C-layout) -> LDS -> A-layout bf16 fragment (wave-local)
#pragma unroll
      for (int r = 0; r < 4; r++){
        wlds[(quad * 4 + r) * 44 + ml]      = p0[r];
        wlds[(quad * 4 + r) * 44 + 16 + ml] = p1[r];
      }
      __asm__ volatile("s_waitcnt lgkmcnt(0)" ::: "memory");
      f32x4 pa = *(const f32x4*)&wlds[ml * 44 + quad * 8];
      f32x4 pb = *(const f32x4*)&wlds[ml * 44 + quad * 8 + 4];
      uint4 pw = { pkbf2(pa[0], pa[1]), pkbf2(pa[2], pa[3]),
                   pkbf2(pb[0], pb[1]), pkbf2(pb[2], pb[3]) };
      short8 pf = *(short8*)&pw;
#pragma unroll
      for (int dt = 0; dt < 4; dt++){
        short8 vf = *(const short8*)&vt_[((long)(kvh * 64 + dt * 16 + ml)) * TT + j0 + quad * 8];
        oa[dt] = __builtin_amdgcn_mfma_f32_16x16x32_bf16(pf, vf, oa[dt], 0, 0, 0);
      }
    }
    // l: reduce across the 16 col-lanes
#pragma unroll
    for (int off = 1; off < 16; off <<= 1){
#pragma unroll
      for (int r = 0; r < 4; r++) l_part[r] += __shfl_xor(l_part[r], off);
    }
    // publish partial O and l
#pragma unroll
    for (int dt = 0; dt < 4; dt++)
#pragma unroll
      for (int r = 0; r < 4; r++)
        wlds[(quad * 4 + r) * 68 + dt * 16 + ml] = oa[dt][r];
    if (ml == 0){
#pragma unroll
      for (int r = 0; r < 4; r++) wlds[1088 + quad * 4 + r] = l_part[r];
    }
    __syncthreads();
    // merge 8 waves: thread -> (row = tid>>5, 2 cols)
    {
      const int row = tid >> 5, c2 = (tid & 31) * 2;
      float L = 0.f; f32x2 s = {0.f, 0.f};
#pragma unroll
      for (int w = 0; w < 8; w++){
        const float* rg = lds + w * 1104;
        L += rg[1088 + row];
        f32x2 t2 = *(const f32x2*)&rg[row * 68 + c2];
        s[0] += t2[0]; s[1] += t2[1];
      }
      float invL = __builtin_amdgcn_rcpf(L);
      *(unsigned int*)&attn_out[(long)(i0 + row) * 1024 + h * 64 + c2] =
          pkbf2(s[0] * invL, s[1] * invL);
    }
    __syncthreads();   // LDS reuse in next phase
  }
  // fused spatial_norm finalize (bpart ready: gemm1 completed before attn)
  if (blockIdx.x == 0 && tid < 64){
    float s = 0.f;
    for (int i = lane; i < 768; i += 64) s += bpart[i];
#pragma unroll
    for (int off = 1; off < 64; off <<= 1) s += __shfl_xor(s, off);
    if (lane == 0) out_scalar[0] = s * (1.f / 32768.f);
  }
}

// ---------------- 4. O-proj GEMM: C[2048,1024] = attn[2048,1024] x owb^T ----------------
__global__ __launch_bounds__(256) void gemm2_kernel(
    const unsigned short* __restrict__ A, const unsigned short* __restrict__ B,
    float* __restrict__ C){
  __shared__ unsigned short As[64 * 32];
  __shared__ unsigned short Bs[64 * 32];
  const int tid = threadIdx.x, lane = tid & 63, wave = tid >> 6;
  const int bm = blockIdx.y * 64, bn = blockIdx.x * 64;
  const int wm = (wave >> 1) * 32, wn = (wave & 1) * 32;
  const int ml = lane & 15, quad = lane >> 4;
  f32x4 acc[2][2];
  const f32x4 z = {0.f, 0.f, 0.f, 0.f};
  acc[0][0] = z; acc[0][1] = z; acc[1][0] = z; acc[1][1] = z;

  const int srow = tid >> 2, scol = (tid & 3) * 8;
  const unsigned short* Ag = A + (long)(bm + srow) * 1024 + scol;
  const unsigned short* Bg = B + (long)(bn + srow) * 1024 + scol;

  for (int kk = 0; kk < 1024; kk += 32){
    __syncthreads();
    *(uint4*)&As[srow * 32 + scol] = *(const uint4*)(Ag + kk);
    *(uint4*)&Bs[srow * 32 + scol] = *(const uint4*)(Bg + kk);
    __syncthreads();
    short8 a0f = *(const short8*)&As[(wm + ml) * 32 + quad * 8];
    short8 a1f = *(const short8*)&As[(wm + 16 + ml) * 32 + quad * 8];
    short8 b0f = *(const short8*)&Bs[(wn + ml) * 32 + quad * 8];
    short8 b1f = *(const short8*)&Bs[(wn + 16 + ml) * 32 + quad * 8];
    acc[0][0] = __builtin_amdgcn_mfma_f32_16x16x32_bf16(a0f, b0f, acc[0][0], 0, 0, 0);
    acc[0][1] = __builtin_amdgcn_mfma_f32_16x16x32_bf16(a0f, b1f, acc[0][1], 0, 0, 0);
    acc[1][0] = __builtin_amdgcn_mfma_f32_16x16x32_bf16(a1f, b0f, acc[1][0], 0, 0, 0);
    acc[1][1] = __builtin_amdgcn_mfma_f32_16x16x32_bf16(a1f, b1f, acc[1][1], 0, 0, 0);
  }
#pragma unroll
  for (int i = 0; i < 2; i++)
#pragma unroll
    for (int j = 0; j < 2; j++)
#pragma unroll
      for (int r = 0; r < 4; r++)
        C[(long)(bm + wm + i * 16 + quad * 4 + r) * 1024 + bn + wn + j * 16 + ml] = acc[i][j][r];
}

extern "C" void kernel_launch(void* const* d_in, const int* in_sizes, int n_in,
                              void* d_out, int out_size, void* d_ws, size_t ws_size,
                              hipStream_t stream){
  const float* x    = (const float*)d_in[0];
  const float* qw   = (const float*)d_in[1];
  const float* kw   = (const float*)d_in[2];
  const float* vw   = (const float*)d_in[3];
  const float* ow   = (const float*)d_in[4];
  const float* temp = (const float*)d_in[5];
  const float* curv = (const float*)d_in[6];
  float* out = (float*)d_out;

  char* ws = (char*)d_ws;
  size_t off = 0;
  auto alloc = [&](size_t bytes) -> char* {
    char* p = ws + off;
    off += (bytes + 255) & ~(size_t)255;
    return p;
  };
  unsigned short* wqkv = (unsigned short*)alloc((size_t)1536 * DM * 2);      // 3 MB
  unsigned short* owb  = (unsigned short*)alloc((size_t)DM * DM * 2);        // 2 MB
  unsigned short* qb   = (unsigned short*)alloc((size_t)NH * TT * HD * 2);   // 4 MB
  unsigned short* kb   = (unsigned short*)alloc((size_t)NKV * TT * HD * 2);  // 1 MB
  unsigned short* vt   = (unsigned short*)alloc((size_t)NKV * TT * HD * 2);  // 1 MB
  float*          q0   = (float*)alloc((size_t)NH * TT * 4);
  float*          k0   = (float*)alloc((size_t)NKV * TT * 4);
  unsigned short* attn = (unsigned short*)alloc((size_t)TT * DM * 2);        // 4 MB
  float*          bpart= (float*)alloc((size_t)768 * 4);

  convertw_kernel<<<2560, 256, 0, stream>>>(qw, kw, vw, ow, wqkv, owb);
  gemm1_fused<<<dim3(24, 32), 256, 0, stream>>>(x, wqkv, qb, kb, vt, q0, k0, bpart, curv);
  attn_kernel<<<1024, 512, 0, stream>>>(qb, kb, vt, q0, k0, temp, curv, attn,
                                        bpart, out + (size_t)TT * DM);
  gemm2_kernel<<<dim3(16, 32), 256, 0, stream>>>(attn, owb, out);
}

// Round 5
// 188.496 us; speedup vs baseline: 1.4286x; 1.0157x over previous
//
#include <hip/hip_runtime.h>
#include <hip/hip_bf16.h>

typedef __attribute__((ext_vector_type(8))) short short8;
typedef __attribute__((ext_vector_type(4))) float f32x4;
typedef __attribute__((ext_vector_type(2))) float f32x2;

#define TT 2048   // sequence length
#define DM 1024   // model dim
#define NH 16     // query heads
#define NKV 4     // kv heads
#define HD 64     // head dim

__device__ __forceinline__ unsigned short f2bf(float x){
  unsigned int u = __float_as_uint(x);
  u += 0x7fffu + ((u >> 16) & 1u);   // RNE
  return (unsigned short)(u >> 16);
}
// packed 2xfp32 -> 2xbf16 (v_cvt_pk_bf16_f32 on gfx950)
__device__ __forceinline__ unsigned int pkbf2(float x, float y){
  union { __hip_bfloat162 h; unsigned int u; } t;
  t.h = __float22bfloat162_rn(make_float2(x, y));
  return t.u;
}

// ---------------- 1. x + weights fp32 -> bf16 ----------------
// vec4 units: x 524288 | q_w 262144 | k_w 65536 | v_w 65536 | o_w 262144 (tot 1179648)
__global__ __launch_bounds__(256) void convertw_kernel(
    const float* __restrict__ x,
    const float* __restrict__ qw, const float* __restrict__ kw,
    const float* __restrict__ vw, const float* __restrict__ ow,
    unsigned short* __restrict__ xb,
    unsigned short* __restrict__ wqkv, unsigned short* __restrict__ owb){
  long v = (long)blockIdx.x * 256 + threadIdx.x;
  const float* src; unsigned short* dst; long base;
  if      (v < 524288) { src = x;  dst = xb;             base = v; }
  else if (v < 786432) { src = qw; dst = wqkv;           base = v - 524288; }
  else if (v < 851968) { src = kw; dst = wqkv + 1048576; base = v - 786432; }
  else if (v < 917504) { src = vw; dst = wqkv + 1310720; base = v - 851968; }
  else                 { src = ow; dst = owb;            base = v - 917504; }
  f32x4 d = *(const f32x4*)(src + base * 4);
  uint2 pk = { pkbf2(d[0], d[1]), pkbf2(d[2], d[3]) };
  *(uint2*)(dst + base * 4) = pk;
}

// ---------------- 2. QKV GEMM + fused RMSNorm/RoPE/q0k0/Vtrans ----
// grid dim3(24, 32): x = head-block (0..15 q | 16..19 k | 20..23 v), y = 64-row t-tile
__global__ __launch_bounds__(256) void gemm1_fused(
    const unsigned short* __restrict__ xb, const unsigned short* __restrict__ wqkv,
    unsigned short* __restrict__ qb, unsigned short* __restrict__ kb,
    unsigned short* __restrict__ vt,
    float* __restrict__ q0, float* __restrict__ k0,
    float* __restrict__ bpart, const float* __restrict__ curv){
  __shared__ float smemf[4160];                 // 16640 B: staging(8KB) then Ct[64][65]
  unsigned short* As = (unsigned short*)smemf;  // [64][32]
  unsigned short* Bs = As + 2048;               // [64][32]
  float* Ct = smemf;
  __shared__ float bsum;
  const int tid = threadIdx.x, lane = tid & 63, wave = tid >> 6;
  const int hIdx = blockIdx.x;
  const int bm = blockIdx.y * 64, bn = hIdx * 64;
  const int wm = (wave >> 1) * 32, wn = (wave & 1) * 32;
  const int ml = lane & 15, quad = lane >> 4;
  if (tid == 0) bsum = 0.f;
  f32x4 acc[2][2];
  const f32x4 z = {0.f, 0.f, 0.f, 0.f};
  acc[0][0] = z; acc[0][1] = z; acc[1][0] = z; acc[1][1] = z;

  const int srow = tid >> 2, scol = (tid & 3) * 8;
  const unsigned short* Ag = xb + (long)(bm + srow) * 1024 + scol;
  const unsigned short* Bg = wqkv + (long)(bn + srow) * 1024 + scol;

  for (int kk = 0; kk < 1024; kk += 32){
    __syncthreads();
    *(uint4*)&As[srow * 32 + scol] = *(const uint4*)(Ag + kk);
    *(uint4*)&Bs[srow * 32 + scol] = *(const uint4*)(Bg + kk);
    __syncthreads();
    short8 a0f = *(const short8*)&As[(wm + ml) * 32 + quad * 8];
    short8 a1f = *(const short8*)&As[(wm + 16 + ml) * 32 + quad * 8];
    short8 b0f = *(const short8*)&Bs[(wn + ml) * 32 + quad * 8];
    short8 b1f = *(const short8*)&Bs[(wn + 16 + ml) * 32 + quad * 8];
    acc[0][0] = __builtin_amdgcn_mfma_f32_16x16x32_bf16(a0f, b0f, acc[0][0], 0, 0, 0);
    acc[0][1] = __builtin_amdgcn_mfma_f32_16x16x32_bf16(a0f, b1f, acc[0][1], 0, 0, 0);
    acc[1][0] = __builtin_amdgcn_mfma_f32_16x16x32_bf16(a1f, b0f, acc[1][0], 0, 0, 0);
    acc[1][1] = __builtin_amdgcn_mfma_f32_16x16x32_bf16(a1f, b1f, acc[1][1], 0, 0, 0);
  }
  __syncthreads();      // staging region -> Ct reuse
#pragma unroll
  for (int i = 0; i < 2; i++)
#pragma unroll
    for (int j = 0; j < 2; j++)
#pragma unroll
      for (int r = 0; r < 4; r++)
        Ct[(wm + i * 16 + quad * 4 + r) * 65 + wn + j * 16 + ml] = acc[i][j][r];
  __syncthreads();

  if (hIdx < 20){
    // RMSNorm + RoPE + q0/k0 (+ spatial partial for q). lane = head-dim d.
    const bool isq = hIdx < 16;
    const int h = isq ? hIdx : hIdx - 16;
    const float c = curv[0];
    unsigned short* ob = isq ? qb : kb;
    float* o0 = isq ? q0 : k0;
#pragma unroll 1
    for (int rr = 0; rr < 16; rr++){
      const int row = wave * 16 + rr;
      const int t = bm + row;
      float val = Ct[row * 65 + lane];
      float ss = val * val;
#pragma unroll
      for (int off = 1; off < 64; off <<= 1) ss += __shfl_xor(ss, off);
      float scale = __builtin_amdgcn_rsqf(ss * (1.f / 64.f) + 1e-6f);
      float xn = val * scale;
      float other = __shfl_xor(xn, 32);
      int fi = lane & 31;
      float ang = (float)t * __builtin_amdgcn_exp2f((float)fi * (-13.287712379549449f / 32.f));
      float sn, cs; __sincosf(ang, &sn, &cs);
      float outv = (lane < 32) ? (xn * cs + other * sn) : (xn * cs - other * sn);
      ob[((long)h * TT + t) * 64 + lane] = f2bf(outv);
      if (lane == 0){
        float sq = ss * scale * scale;      // |normed|^2, rope preserves norm
        o0[h * TT + t] = __builtin_amdgcn_sqrtf(1.f / c + sq);
        if (isq) atomicAdd(&bsum, __builtin_amdgcn_sqrtf(sq));
      }
    }
  } else {
    // V: bf16 + transpose to vt[hk][d][t]
    const int hk = hIdx - 20;
    const int d = tid >> 2, tseg = (tid & 3) * 16;
    uint4 w0, w1;
    w0.x = pkbf2(Ct[(tseg + 0) * 65 + d], Ct[(tseg + 1) * 65 + d]);
    w0.y = pkbf2(Ct[(tseg + 2) * 65 + d], Ct[(tseg + 3) * 65 + d]);
    w0.z = pkbf2(Ct[(tseg + 4) * 65 + d], Ct[(tseg + 5) * 65 + d]);
    w0.w = pkbf2(Ct[(tseg + 6) * 65 + d], Ct[(tseg + 7) * 65 + d]);
    w1.x = pkbf2(Ct[(tseg + 8) * 65 + d], Ct[(tseg + 9) * 65 + d]);
    w1.y = pkbf2(Ct[(tseg +10) * 65 + d], Ct[(tseg +11) * 65 + d]);
    w1.z = pkbf2(Ct[(tseg +12) * 65 + d], Ct[(tseg +13) * 65 + d]);
    w1.w = pkbf2(Ct[(tseg +14) * 65 + d], Ct[(tseg +15) * 65 + d]);
    unsigned short* dst = vt + (long)(hk * 64 + d) * TT + bm + tseg;
    *(uint4*)dst = w0;
    *(uint4*)(dst + 8) = w1;
  }
  __syncthreads();
  if (tid == 0) bpart[blockIdx.y * 24 + hIdx] = bsum;
}

// ---------------- 3. balanced hyperbolic causal attention, S^T orientation ----------
// block = 256 thr (4 waves); q-tiles {127-pair, pair} -> exactly 65 j-tiles/block.
// S^T = MFMA(K, Q): key=quad*4+r, q=ml.  O^T = MFMA(V^T, P): d=quad*4+r, q=ml.
// P (C-layout of S^T) -> B-fragment via 8 ds_bpermute, no LDS round-trip in loop.
__global__ __launch_bounds__(256, 4) void attn_kernel(
    const unsigned short* __restrict__ qb_, const unsigned short* __restrict__ kb_,
    const unsigned short* __restrict__ vt_,
    const float* __restrict__ q0_, const float* __restrict__ k0_,
    const float* __restrict__ temp, const float* __restrict__ curv,
    unsigned short* __restrict__ attn_out,
    const float* __restrict__ bpart, float* __restrict__ out_scalar){
  __shared__ float lds[4 * 1104];    // per-wave merge: O^T as [16q][68] + l[16] at 1088
  const int tid = threadIdx.x, lane = tid & 63, wave = tid >> 6;
  float* wlds = lds + wave * 1104;
  const int h = blockIdx.x & 15, pair = blockIdx.x >> 4;
  const int kvh = h >> 2;
  const int ml = lane & 15, quad = lane >> 4;
  const float c = curv[0];
  const float factor = -1.f / (__builtin_amdgcn_sqrtf(c) * temp[h]);
  const f32x4 z = {0.f, 0.f, 0.f, 0.f};
  const int srcA = ml + ((quad & 1) << 5);   // bpermute source lanes
  const int srcB = srcA + 16;
  const bool selA = quad < 2;
  const unsigned short* kh = kb_ + (long)kvh * TT * 64;
  const float* k0h = k0_ + kvh * TT;

#pragma unroll 1
  for (int ph = 0; ph < 2; ph++){
    const int qt = ph ? pair : 127 - pair;
    const int i0 = qt * 16;
    short8 qf0 = *(const short8*)&qb_[((long)h * TT + i0 + ml) * 64 + quad * 8];
    short8 qf1 = *(const short8*)&qb_[((long)h * TT + i0 + ml) * 64 + 32 + quad * 8];
    const float q0c = c * q0_[h * TT + i0 + ml];   // per-lane: q = i0+ml
    const int rowq = i0 + ml;
    f32x4 oa[4];
#pragma unroll
    for (int dt = 0; dt < 4; dt++) oa[dt] = z;
    float l_sum = 0.f;

    const int nt = (i0 + 47) >> 5;
    // prefetch first K tile for this wave
    short8 nk0, nk1, nk2, nk3;
    if (wave < nt){
      const unsigned short* kp = kh + ((long)(wave << 5)) * 64;
      nk0 = *(const short8*)(kp + ml * 64 + quad * 8);
      nk1 = *(const short8*)(kp + ml * 64 + 32 + quad * 8);
      nk2 = *(const short8*)(kp + (16 + ml) * 64 + quad * 8);
      nk3 = *(const short8*)(kp + (16 + ml) * 64 + 32 + quad * 8);
    }
#pragma unroll 1
    for (int t = wave; t < nt; t += 4){
      const int j0 = t << 5;
      short8 ka0 = nk0, ka1 = nk1, kc0 = nk2, kc1 = nk3;
      if (t + 4 < nt){   // prefetch next tile during this tile's compute
        const unsigned short* kp = kh + ((long)((t + 4) << 5)) * 64;
        nk0 = *(const short8*)(kp + ml * 64 + quad * 8);
        nk1 = *(const short8*)(kp + ml * 64 + 32 + quad * 8);
        nk2 = *(const short8*)(kp + (16 + ml) * 64 + quad * 8);
        nk3 = *(const short8*)(kp + (16 + ml) * 64 + 32 + quad * 8);
      }
      // k0 for this tile's keys (16B vector loads, quad-replicated)
      f32x4 k0a = *(const f32x4*)(k0h + j0 + quad * 4);
      f32x4 k0b = *(const f32x4*)(k0h + j0 + 16 + quad * 4);
      // V fragments (A-operand of PV), issued early
      short8 vf0 = *(const short8*)&vt_[((long)(kvh * 64 +  0 + ml)) * TT + j0 + quad * 8];
      short8 vf1 = *(const short8*)&vt_[((long)(kvh * 64 + 16 + ml)) * TT + j0 + quad * 8];
      short8 vf2 = *(const short8*)&vt_[((long)(kvh * 64 + 32 + ml)) * TT + j0 + quad * 8];
      short8 vf3 = *(const short8*)&vt_[((long)(kvh * 64 + 48 + ml)) * TT + j0 + quad * 8];

      f32x4 s0 = z, s1 = z;     // S^T: keys j0+quad*4+r (s0) / +16 (s1), q=ml
      s0 = __builtin_amdgcn_mfma_f32_16x16x32_bf16(ka0, qf0, s0, 0, 0, 0);
      s0 = __builtin_amdgcn_mfma_f32_16x16x32_bf16(ka1, qf1, s0, 0, 0, 0);
      s1 = __builtin_amdgcn_mfma_f32_16x16x32_bf16(kc0, qf0, s1, 0, 0, 0);
      s1 = __builtin_amdgcn_mfma_f32_16x16x32_bf16(kc1, qf1, s1, 0, 0, 0);

      const bool nm = (j0 + 31 > i0);
      const int keyb = j0 + quad * 4;
      float p0[4], p1[4];
#pragma unroll
      for (int r = 0; r < 4; r++){
        float argA = fmaxf(__builtin_fmaf(-c, s0[r], q0c * k0a[r]), 1.00001f);
        float wA   = argA + __builtin_amdgcn_sqrtf(__builtin_fmaf(argA, argA, -1.f));
        float pA   = __builtin_amdgcn_exp2f(factor * __builtin_amdgcn_logf(wA));
        float argB = fmaxf(__builtin_fmaf(-c, s1[r], q0c * k0b[r]), 1.00001f);
        float wB   = argB + __builtin_amdgcn_sqrtf(__builtin_fmaf(argB, argB, -1.f));
        float pB   = __builtin_amdgcn_exp2f(factor * __builtin_amdgcn_logf(wB));
        if (nm){
          if (keyb + r > rowq)      pA = 0.f;
          if (keyb + 16 + r > rowq) pB = 0.f;
        }
        p0[r] = pA; p1[r] = pB;
        l_sum += pA + pB;
      }
      // pack P^T -> bf16 pairs, then build B-fragment via bpermute
      int a0 = (int)pkbf2(p0[0], p0[1]), a1 = (int)pkbf2(p0[2], p0[3]);
      int b0 = (int)pkbf2(p1[0], p1[1]), b1 = (int)pkbf2(p1[2], p1[3]);
      int xA0 = __shfl(a0, srcA), xB0 = __shfl(b0, srcA);
      int xA1 = __shfl(a1, srcA), xB1 = __shfl(b1, srcA);
      int xA2 = __shfl(a0, srcB), xB2 = __shfl(b0, srcB);
      int xA3 = __shfl(a1, srcB), xB3 = __shfl(b1, srcB);
      int w4[4] = { selA ? xA0 : xB0, selA ? xA1 : xB1,
                    selA ? xA2 : xB2, selA ? xA3 : xB3 };
      short8 pf = *(short8*)w4;
      oa[0] = __builtin_amdgcn_mfma_f32_16x16x32_bf16(vf0, pf, oa[0], 0, 0, 0);
      oa[1] = __builtin_amdgcn_mfma_f32_16x16x32_bf16(vf1, pf, oa[1], 0, 0, 0);
      oa[2] = __builtin_amdgcn_mfma_f32_16x16x32_bf16(vf2, pf, oa[2], 0, 0, 0);
      oa[3] = __builtin_amdgcn_mfma_f32_16x16x32_bf16(vf3, pf, oa[3], 0, 0, 0);
    }
    // l across quads (keys were split across quads+regs; q=ml fixed)
    l_sum += __shfl_xor(l_sum, 16);
    l_sum += __shfl_xor(l_sum, 32);
    // publish wave partials: O^T reg r -> d = dt*16+quad*4+r at q=ml
#pragma unroll
    for (int dt = 0; dt < 4; dt++)
      *(f32x4*)&wlds[ml * 68 + dt * 16 + quad * 4] = oa[dt];
    if (quad == 0) wlds[1088 + ml] = l_sum;
    __syncthreads();
    // merge 4 waves: thread -> (row = tid>>4, 4 d's)
    {
      const int row = tid >> 4, c0 = (tid & 15) * 4;
      float L = 0.f; f32x4 s = z;
#pragma unroll
      for (int w = 0; w < 4; w++){
        const float* rg = lds + w * 1104;
        L += rg[1088 + row];
        f32x4 t2 = *(const f32x4*)&rg[row * 68 + c0];
        s[0] += t2[0]; s[1] += t2[1]; s[2] += t2[2]; s[3] += t2[3];
      }
      float invL = __builtin_amdgcn_rcpf(L);
      uint2 o = { pkbf2(s[0] * invL, s[1] * invL), pkbf2(s[2] * invL, s[3] * invL) };
      *(uint2*)&attn_out[(long)(i0 + row) * 1024 + h * 64 + c0] = o;
    }
    __syncthreads();   // LDS reuse in next phase
  }
  // fused spatial_norm finalize (bpart ready: gemm1 completed before attn)
  if (blockIdx.x == 0 && tid < 64){
    float s = 0.f;
    for (int i = lane; i < 768; i += 64) s += bpart[i];
#pragma unroll
    for (int off = 1; off < 64; off <<= 1) s += __shfl_xor(s, off);
    if (lane == 0) out_scalar[0] = s * (1.f / 32768.f);
  }
}

// ---------------- 4. O-proj GEMM: C[2048,1024] = attn[2048,1024] x owb^T ----------------
__global__ __launch_bounds__(256) void gemm2_kernel(
    const unsigned short* __restrict__ A, const unsigned short* __restrict__ B,
    float* __restrict__ C){
  __shared__ unsigned short As[64 * 32];
  __shared__ unsigned short Bs[64 * 32];
  const int tid = threadIdx.x, lane = tid & 63, wave = tid >> 6;
  const int bm = blockIdx.y * 64, bn = blockIdx.x * 64;
  const int wm = (wave >> 1) * 32, wn = (wave & 1) * 32;
  const int ml = lane & 15, quad = lane >> 4;
  f32x4 acc[2][2];
  const f32x4 z = {0.f, 0.f, 0.f, 0.f};
  acc[0][0] = z; acc[0][1] = z; acc[1][0] = z; acc[1][1] = z;

  const int srow = tid >> 2, scol = (tid & 3) * 8;
  const unsigned short* Ag = A + (long)(bm + srow) * 1024 + scol;
  const unsigned short* Bg = B + (long)(bn + srow) * 1024 + scol;

  for (int kk = 0; kk < 1024; kk += 32){
    __syncthreads();
    *(uint4*)&As[srow * 32 + scol] = *(const uint4*)(Ag + kk);
    *(uint4*)&Bs[srow * 32 + scol] = *(const uint4*)(Bg + kk);
    __syncthreads();
    short8 a0f = *(const short8*)&As[(wm + ml) * 32 + quad * 8];
    short8 a1f = *(const short8*)&As[(wm + 16 + ml) * 32 + quad * 8];
    short8 b0f = *(const short8*)&Bs[(wn + ml) * 32 + quad * 8];
    short8 b1f = *(const short8*)&Bs[(wn + 16 + ml) * 32 + quad * 8];
    acc[0][0] = __builtin_amdgcn_mfma_f32_16x16x32_bf16(a0f, b0f, acc[0][0], 0, 0, 0);
    acc[0][1] = __builtin_amdgcn_mfma_f32_16x16x32_bf16(a0f, b1f, acc[0][1], 0, 0, 0);
    acc[1][0] = __builtin_amdgcn_mfma_f32_16x16x32_bf16(a1f, b0f, acc[1][0], 0, 0, 0);
    acc[1][1] = __builtin_amdgcn_mfma_f32_16x16x32_bf16(a1f, b1f, acc[1][1], 0, 0, 0);
  }
#pragma unroll
  for (int i = 0; i < 2; i++)
#pragma unroll
    for (int j = 0; j < 2; j++)
#pragma unroll
      for (int r = 0; r < 4; r++)
        C[(long)(bm + wm + i * 16 + quad * 4 + r) * 1024 + bn + wn + j * 16 + ml] = acc[i][j][r];
}

extern "C" void kernel_launch(void* const* d_in, const int* in_sizes, int n_in,
                              void* d_out, int out_size, void* d_ws, size_t ws_size,
                              hipStream_t stream){
  const float* x    = (const float*)d_in[0];
  const float* qw   = (const float*)d_in[1];
  const float* kw   = (const float*)d_in[2];
  const float* vw   = (const float*)d_in[3];
  const float* ow   = (const float*)d_in[4];
  const float* temp = (const float*)d_in[5];
  const float* curv = (const float*)d_in[6];
  float* out = (float*)d_out;

  char* ws = (char*)d_ws;
  size_t off = 0;
  auto alloc = [&](size_t bytes) -> char* {
    char* p = ws + off;
    off += (bytes + 255) & ~(size_t)255;
    return p;
  };
  unsigned short* xb   = (unsigned short*)alloc((size_t)TT * DM * 2);        // 4 MB
  unsigned short* wqkv = (unsigned short*)alloc((size_t)1536 * DM * 2);      // 3 MB
  unsigned short* owb  = (unsigned short*)alloc((size_t)DM * DM * 2);        // 2 MB
  unsigned short* qb   = (unsigned short*)alloc((size_t)NH * TT * HD * 2);   // 4 MB
  unsigned short* kb   = (unsigned short*)alloc((size_t)NKV * TT * HD * 2);  // 1 MB
  unsigned short* vt   = (unsigned short*)alloc((size_t)NKV * TT * HD * 2);  // 1 MB
  float*          q0   = (float*)alloc((size_t)NH * TT * 4);
  float*          k0   = (float*)alloc((size_t)NKV * TT * 4);
  unsigned short* attn = (unsigned short*)alloc((size_t)TT * DM * 2);        // 4 MB
  float*          bpart= (float*)alloc((size_t)768 * 4);

  convertw_kernel<<<4608, 256, 0, stream>>>(x, qw, kw, vw, ow, xb, wqkv, owb);
  gemm1_fused<<<dim3(24, 32), 256, 0, stream>>>(xb, wqkv, qb, kb, vt, q0, k0, bpart, curv);
  attn_kernel<<<1024, 256, 0, stream>>>(qb, kb, vt, q0, k0, temp, curv, attn,
                                        bpart, out + (size_t)TT * DM);
  gemm2_kernel<<<dim3(16, 32), 256, 0, stream>>>(attn, owb, out);
}